// Round 2
// baseline (509.793 us; speedup 1.0000x reference)
//
#include <hip/hip_runtime.h>
#include <math.h>

#define B 128
#define H 4
#define N 4096
#define W 128
#define CTRL (H*(3*W+6))   // 1560
#define EPSF 1e-8f

__device__ __forceinline__ float sigmoidf_(float x){ return 1.0f/(1.0f+expf(-x)); }
__device__ __forceinline__ float softplusf_(float x){ return (x>20.0f)? x : log1pf(expf(x)); }
// strictly-positive base fast pow: t > 0 guaranteed by construction
__device__ __forceinline__ float pospowf_(float t, float g){ return exp2f(g * log2f(t)); }

// ---- block reduction helpers (256 threads = 4 waves of 64) ----
__device__ __forceinline__ float blockReduceSum256(float v, float* red){
  int tid = threadIdx.x;
  #pragma unroll
  for (int off=32; off>0; off>>=1) v += __shfl_xor(v, off);
  __syncthreads();                 // protect red reuse from prior call
  if ((tid&63)==0) red[tid>>6] = v;
  __syncthreads();
  return red[0]+red[1]+red[2]+red[3];
}
__device__ __forceinline__ float blockReduceMax256(float v, float* red){
  int tid = threadIdx.x;
  #pragma unroll
  for (int off=32; off>0; off>>=1) v = fmaxf(v, __shfl_xor(v, off));
  __syncthreads();
  if ((tid&63)==0) red[tid>>6] = v;
  __syncthreads();
  return fmaxf(fmaxf(red[0],red[1]), fmaxf(red[2],red[3]));
}

// ---- kernel 1: control prep ----
__global__ __launch_bounds__(128) void prep_kernel(const float* __restrict__ controls,
    float* __restrict__ keys_t, float* __restrict__ erase_s, float* __restrict__ write_t,
    float* __restrict__ scal){
  int bh = blockIdx.x;
  int b = bh >> 2, h = bh & (H-1);
  int w = threadIdx.x;
  const float* c = controls + (size_t)b*CTRL;
  float k = tanhf(c[h*W + w]);
  keys_t [bh*W + w] = k;
  erase_s[bh*W + w] = sigmoidf_(c[1*H*W + h*W + w]);
  write_t[bh*W + w] = tanhf   (c[2*H*W + h*W + w]);
  __shared__ float red[128];
  red[w] = k*k;
  __syncthreads();
  for (int s=64; s>0; s>>=1){ if (w<s) red[w] += red[w+s]; __syncthreads(); }
  if (w==0){
    float knorm = sqrtf(red[0]);
    float beta  = softplusf_(c[3*H*W + h]);
    float gate  = sigmoidf_ (c[3*H*W + H + h]);
    float s0r = c[3*H*W + 2*H + h*3 + 0];
    float s1r = c[3*H*W + 2*H + h*3 + 1];
    float s2r = c[3*H*W + 2*H + h*3 + 2];
    float m = fmaxf(s0r, fmaxf(s1r, s2r));
    float e0 = expf(s0r-m), e1 = expf(s1r-m), e2 = expf(s2r-m);
    float inv = 1.0f/(e0+e1+e2);
    float gamma = 1.0f + softplusf_(c[3*H*W + 5*H + h]);
    float* sc = scal + bh*8;
    sc[0]=beta; sc[1]=gate; sc[2]=e0*inv; sc[3]=e1*inv; sc[4]=e2*inv; sc[5]=gamma; sc[6]=knorm;
  }
}

// ---- kernel 1b: prev_weights = softmax(bias) per head, batch-independent ----
__global__ __launch_bounds__(256) void bias_softmax_kernel(const float* __restrict__ bias,
    float* __restrict__ pw){
  int h = blockIdx.x;
  int tid = threadIdx.x;
  __shared__ float red[4];
  const float4* brow = (const float4*)(bias + (size_t)h*N);
  float4 p[4]; float lm = -1e30f;
  #pragma unroll
  for (int j=0;j<4;j++){
    p[j] = brow[tid + 256*j];
    lm = fmaxf(lm, fmaxf(fmaxf(p[j].x,p[j].y), fmaxf(p[j].z,p[j].w)));
  }
  float m = blockReduceMax256(lm, red);
  float ls = 0.0f;
  #pragma unroll
  for (int j=0;j<4;j++){
    p[j].x = expf(p[j].x-m); p[j].y = expf(p[j].y-m);
    p[j].z = expf(p[j].z-m); p[j].w = expf(p[j].w-m);
    ls += p[j].x+p[j].y+p[j].z+p[j].w;
  }
  float s = blockReduceSum256(ls, red);
  float inv = 1.0f/s;
  float4* orow = (float4*)(pw + (size_t)h*N);
  #pragma unroll
  for (int j=0;j<4;j++)
    orow[tid + 256*j] = make_float4(p[j].x*inv, p[j].y*inv, p[j].z*inv, p[j].w*inv);
}

// ---- kernel 2: beta-scaled cosine scores [B,H,N] ----
// 16 lanes per memory row (8 floats each via 2x float4); one wave = 4 rows at a
// time; butterfly is 4 steps over 16 lanes shared across the wave's rows.
__global__ __launch_bounds__(256) void scores_kernel(const float* __restrict__ memory,
    const float* __restrict__ keys_t, const float* __restrict__ scal,
    float* __restrict__ scores){
  int b = blockIdx.y;
  int n0 = blockIdx.x * 64;
  int tid = threadIdx.x;
  int grp = tid >> 4, l16 = tid & 15;     // 16 groups of 16 lanes
  __shared__ __align__(16) float kk[H][W];
  __shared__ float kbeta[H], kn[H];
  for (int i = tid; i < H*W; i += 256) kk[0][i] = keys_t[(size_t)b*H*W + i];
  if (tid < H){ kbeta[tid] = scal[(b*H+tid)*8 + 0]; kn[tid] = scal[(b*H+tid)*8 + 6]; }
  __syncthreads();
  float4 ka[H], kb[H];
  #pragma unroll
  for (int h=0;h<H;h++){
    ka[h] = *(const float4*)&kk[h][l16*8];
    kb[h] = *(const float4*)&kk[h][l16*8+4];
  }
  float beta_l = (l16 < H) ? kbeta[l16] : 0.0f;
  float kn_l   = (l16 < H) ? kn[l16]    : 1.0f;
  #pragma unroll
  for (int it=0; it<4; ++it){
    int n = n0 + it*16 + grp;
    const float4* mp = (const float4*)(memory + ((size_t)b*N + n)*W + l16*8);
    float4 ma = mp[0], mb = mp[1];
    float msq = ma.x*ma.x+ma.y*ma.y+ma.z*ma.z+ma.w*ma.w
              + mb.x*mb.x+mb.y*mb.y+mb.z*mb.z+mb.w*mb.w;
    float d0 = ma.x*ka[0].x+ma.y*ka[0].y+ma.z*ka[0].z+ma.w*ka[0].w
             + mb.x*kb[0].x+mb.y*kb[0].y+mb.z*kb[0].z+mb.w*kb[0].w;
    float d1 = ma.x*ka[1].x+ma.y*ka[1].y+ma.z*ka[1].z+ma.w*ka[1].w
             + mb.x*kb[1].x+mb.y*kb[1].y+mb.z*kb[1].z+mb.w*kb[1].w;
    float d2 = ma.x*ka[2].x+ma.y*ka[2].y+ma.z*ka[2].z+ma.w*ka[2].w
             + mb.x*kb[2].x+mb.y*kb[2].y+mb.z*kb[2].z+mb.w*kb[2].w;
    float d3 = ma.x*ka[3].x+ma.y*ka[3].y+ma.z*ka[3].z+ma.w*ka[3].w
             + mb.x*kb[3].x+mb.y*kb[3].y+mb.z*kb[3].z+mb.w*kb[3].w;
    #pragma unroll
    for (int off=1; off<16; off<<=1){
      msq += __shfl_xor(msq, off);
      d0  += __shfl_xor(d0 , off);
      d1  += __shfl_xor(d1 , off);
      d2  += __shfl_xor(d2 , off);
      d3  += __shfl_xor(d3 , off);
    }
    if (l16 < H){
      float dd = (l16==0)?d0 : (l16==1)?d1 : (l16==2)?d2 : d3;
      float mn = sqrtf(msq);
      scores[((size_t)(b*H + l16))*N + n] = beta_l*dd/(kn_l*mn + EPSF);
    }
  }
}

// ---- kernel 3: softmax -> interp -> circular conv -> sharpen -> write_dist ----
// grid = B*H blocks, 256 threads, float4 everywhere. wd may alias scores:
// every thread's global reads precede its global writes (barriers between).
__global__ __launch_bounds__(256) void dist_kernel(const float* scores,
    const float* __restrict__ pw, const float* __restrict__ scal, float* wd){
  int bh = blockIdx.x;
  int h = bh & (H-1);
  int tid = threadIdx.x;
  __shared__ __align__(16) float buf[N];    // 16 KB
  __shared__ float red[4];
  const float4* srow4 = (const float4*)(scores + (size_t)bh*N);

  float4 v[4]; float lmax = -1e30f;
  #pragma unroll
  for (int j=0;j<4;j++){
    v[j] = srow4[tid + 256*j];
    lmax = fmaxf(lmax, fmaxf(fmaxf(v[j].x,v[j].y), fmaxf(v[j].z,v[j].w)));
  }
  float smax = blockReduceMax256(lmax, red);
  float lsum = 0.0f;
  #pragma unroll
  for (int j=0;j<4;j++){
    v[j].x = expf(v[j].x-smax); v[j].y = expf(v[j].y-smax);
    v[j].z = expf(v[j].z-smax); v[j].w = expf(v[j].w-smax);
    lsum += v[j].x+v[j].y+v[j].z+v[j].w;
  }
  float ssum = blockReduceSum256(lsum, red);

  float gate = scal[bh*8+1];
  float ga = gate/ssum, gb = 1.0f - gate;
  const float4* prow4 = (const float4*)(pw + (size_t)h*N);
  #pragma unroll
  for (int j=0;j<4;j++){
    float4 p = prow4[tid + 256*j];
    float4 o;
    o.x = ga*v[j].x + gb*p.x;  o.y = ga*v[j].y + gb*p.y;
    o.z = ga*v[j].z + gb*p.z;  o.w = ga*v[j].w + gb*p.w;
    ((float4*)buf)[tid + 256*j] = o;
  }
  __syncthreads();

  float s0 = scal[bh*8+2], s1 = scal[bh*8+3], s2 = scal[bh*8+4], gamma = scal[bh*8+5];
  float4 q[4]; float qsum = 0.0f;
  #pragma unroll
  for (int j=0;j<4;j++){
    int m = 4*(tid + 256*j);
    float4 c = *(const float4*)&buf[m];
    float wm = buf[(m + N - 1) & (N-1)];
    float wp = buf[(m + 4) & (N-1)];
    float t0 = s0*wm  + s1*c.x + s2*c.y;
    float t1 = s0*c.x + s1*c.y + s2*c.z;
    float t2 = s0*c.y + s1*c.z + s2*c.w;
    float t3 = s0*c.z + s1*c.w + s2*wp;
    // wsft strictly > 0 (convex mix of positive softmaxes, shift wts >= 0 sum 1)
    q[j].x = pospowf_(t0, gamma); q[j].y = pospowf_(t1, gamma);
    q[j].z = pospowf_(t2, gamma); q[j].w = pospowf_(t3, gamma);
    qsum += q[j].x+q[j].y+q[j].z+q[j].w;
  }
  float tot = blockReduceSum256(qsum, red);
  float inv = 1.0f/(tot + EPSF);
  float4* wrow4 = (float4*)(wd + (size_t)bh*N);
  #pragma unroll
  for (int j=0;j<4;j++)
    wrow4[tid + 256*j] = make_float4(q[j].x*inv, q[j].y*inv, q[j].z*inv, q[j].w*inv);
}

// ---- kernel 4: out = memory * prod_h(1 - wd*erase) + sum_h wd*write ----
// Walks memory in REVERSE block order: scores_kernel streamed memory (256 MB =
// L3 size) front-to-back, so the tail is still L3-resident — reversed traversal
// turns the re-read into L3 hits instead of guaranteed-evicted misses.
__global__ __launch_bounds__(256) void final_kernel(const float* __restrict__ memory,
    const float* __restrict__ wd, const float* __restrict__ erase_s,
    const float* __restrict__ write_t, float* __restrict__ out){
  int b  = (B-1) - blockIdx.y;
  int n0 = ((N/64-1) - blockIdx.x) * 64;
  int tid = threadIdx.x;
  __shared__ __align__(16) float esh[H][W];
  __shared__ __align__(16) float wsh[H][W];
  __shared__ float wdsh[H][64];
  for (int i=tid;i<H*W;i+=256){ esh[0][i] = erase_s[(size_t)b*H*W+i]; wsh[0][i] = write_t[(size_t)b*H*W+i]; }
  for (int i=tid;i<H*64;i+=256){ int h=i>>6, r=i&63; wdsh[h][r] = wd[((size_t)(b*H+h))*N + n0 + r]; }
  __syncthreads();
  int wq = (tid & 31) * 4;   // float4 column
  int rl = tid >> 5;         // row-in-group 0..7
  for (int r = rl; r < 64; r += 8){
    int n = n0 + r;
    size_t base = ((size_t)b*N + n)*W + wq;
    float4 m = *(const float4*)(memory + base);
    float4 prod = make_float4(1.f,1.f,1.f,1.f);
    float4 upd  = make_float4(0.f,0.f,0.f,0.f);
    #pragma unroll
    for (int h=0;h<H;h++){
      float d = wdsh[h][r];
      float4 e  = *(const float4*)&esh[h][wq];
      float4 wv = *(const float4*)&wsh[h][wq];
      prod.x *= 1.0f - d*e.x;  prod.y *= 1.0f - d*e.y;
      prod.z *= 1.0f - d*e.z;  prod.w *= 1.0f - d*e.w;
      upd.x += d*wv.x;  upd.y += d*wv.y;  upd.z += d*wv.z;  upd.w += d*wv.w;
    }
    float4 o;
    o.x = m.x*prod.x + upd.x;  o.y = m.y*prod.y + upd.y;
    o.z = m.z*prod.z + upd.z;  o.w = m.w*prod.w + upd.w;
    *(float4*)(out + base) = o;
  }
}

extern "C" void kernel_launch(void* const* d_in, const int* in_sizes, int n_in,
                              void* d_out, int out_size, void* d_ws, size_t ws_size,
                              hipStream_t stream){
  const float* memory   = (const float*)d_in[0];
  const float* controls = (const float*)d_in[1];
  const float* bias     = (const float*)d_in[2];
  float* out = (float*)d_out;

  float* ws      = (float*)d_ws;
  float* keys_t  = ws;                    // B*H*W
  float* erase_s = keys_t  + B*H*W;       // B*H*W
  float* write_t = erase_s + B*H*W;       // B*H*W
  float* scal    = write_t + B*H*W;       // B*H*8
  float* pw      = scal    + B*H*8;       // H*N (prev_weights = softmax(bias))
  float* scores  = pw      + H*N;         // B*H*N
  float* wd      = scores;                // aliased over scores (safe, see dist_kernel)
  // total ws use: 3*65536 + 4096 + 16384 + 2097152 floats ≈ 8.9 MB

  prep_kernel        <<<dim3(B*H),      dim3(W),   0, stream>>>(controls, keys_t, erase_s, write_t, scal);
  bias_softmax_kernel<<<dim3(H),        dim3(256), 0, stream>>>(bias, pw);
  scores_kernel      <<<dim3(N/64, B),  dim3(256), 0, stream>>>(memory, keys_t, scal, scores);
  dist_kernel        <<<dim3(B*H),      dim3(256), 0, stream>>>(scores, pw, scal, wd);
  final_kernel       <<<dim3(N/64, B),  dim3(256), 0, stream>>>(memory, wd, erase_s, write_t, out);
}

// Round 3
// 498.497 us; speedup vs baseline: 1.0227x; 1.0227x over previous
//
#include <hip/hip_runtime.h>
#include <math.h>

#define B 128
#define H 4
#define N 4096
#define W 128
#define CTRL (H*(3*W+6))   // 1560
#define EPSF 1e-8f

typedef float f32x4 __attribute__((ext_vector_type(4)));

__device__ __forceinline__ float sigmoidf_(float x){ return 1.0f/(1.0f+expf(-x)); }
__device__ __forceinline__ float softplusf_(float x){ return (x>20.0f)? x : log1pf(expf(x)); }
// strictly-positive base fast pow: t > 0 guaranteed by construction
__device__ __forceinline__ float pospowf_(float t, float g){ return exp2f(g * log2f(t)); }

// ---- block reduction helpers (256 threads = 4 waves of 64) ----
__device__ __forceinline__ float blockReduceSum256(float v, float* red){
  int tid = threadIdx.x;
  #pragma unroll
  for (int off=32; off>0; off>>=1) v += __shfl_xor(v, off);
  __syncthreads();                 // protect red reuse from prior call
  if ((tid&63)==0) red[tid>>6] = v;
  __syncthreads();
  return red[0]+red[1]+red[2]+red[3];
}
__device__ __forceinline__ float blockReduceMax256(float v, float* red){
  int tid = threadIdx.x;
  #pragma unroll
  for (int off=32; off>0; off>>=1) v = fmaxf(v, __shfl_xor(v, off));
  __syncthreads();
  if ((tid&63)==0) red[tid>>6] = v;
  __syncthreads();
  return fmaxf(fmaxf(red[0],red[1]), fmaxf(red[2],red[3]));
}

// ---- kernel 1: control prep + (blocks >= B*H) bias softmax ----
// grid = B*H + H blocks, 128 threads.
__global__ __launch_bounds__(128) void prep_kernel(const float* __restrict__ controls,
    float* __restrict__ keys_t, float* __restrict__ erase_s, float* __restrict__ write_t,
    float* __restrict__ scal, const float* __restrict__ bias, float* __restrict__ pw){
  int bid = blockIdx.x;
  int tid = threadIdx.x;
  if (bid >= B*H){
    // ---- prev_weights = softmax(bias) for head h (batch-independent) ----
    int h = bid - B*H;
    __shared__ float red2[2];
    const float4* brow = (const float4*)(bias + (size_t)h*N);
    float4 p[8]; float lm = -1e30f;
    #pragma unroll
    for (int j=0;j<8;j++){
      p[j] = brow[tid + 128*j];
      lm = fmaxf(lm, fmaxf(fmaxf(p[j].x,p[j].y), fmaxf(p[j].z,p[j].w)));
    }
    #pragma unroll
    for (int off=32; off>0; off>>=1) lm = fmaxf(lm, __shfl_xor(lm, off));
    if ((tid&63)==0) red2[tid>>6] = lm;
    __syncthreads();
    float m = fmaxf(red2[0], red2[1]);
    float ls = 0.0f;
    #pragma unroll
    for (int j=0;j<8;j++){
      p[j].x = expf(p[j].x-m); p[j].y = expf(p[j].y-m);
      p[j].z = expf(p[j].z-m); p[j].w = expf(p[j].w-m);
      ls += p[j].x+p[j].y+p[j].z+p[j].w;
    }
    #pragma unroll
    for (int off=32; off>0; off>>=1) ls += __shfl_xor(ls, off);
    __syncthreads();
    if ((tid&63)==0) red2[tid>>6] = ls;
    __syncthreads();
    float inv = 1.0f/(red2[0]+red2[1]);
    float4* orow = (float4*)(pw + (size_t)h*N);
    #pragma unroll
    for (int j=0;j<8;j++)
      orow[tid + 128*j] = make_float4(p[j].x*inv, p[j].y*inv, p[j].z*inv, p[j].w*inv);
    return;
  }
  // ---- control prep for (b,h) ----
  int b = bid >> 2, h = bid & (H-1);
  int w = tid;
  const float* c = controls + (size_t)b*CTRL;
  float k = tanhf(c[h*W + w]);
  keys_t [bid*W + w] = k;
  erase_s[bid*W + w] = sigmoidf_(c[1*H*W + h*W + w]);
  write_t[bid*W + w] = tanhf   (c[2*H*W + h*W + w]);
  __shared__ float red[128];
  red[w] = k*k;
  __syncthreads();
  for (int s=64; s>0; s>>=1){ if (w<s) red[w] += red[w+s]; __syncthreads(); }
  if (w==0){
    float knorm = sqrtf(red[0]);
    float beta  = softplusf_(c[3*H*W + h]);
    float gate  = sigmoidf_ (c[3*H*W + H + h]);
    float s0r = c[3*H*W + 2*H + h*3 + 0];
    float s1r = c[3*H*W + 2*H + h*3 + 1];
    float s2r = c[3*H*W + 2*H + h*3 + 2];
    float mm = fmaxf(s0r, fmaxf(s1r, s2r));
    float e0 = expf(s0r-mm), e1 = expf(s1r-mm), e2 = expf(s2r-mm);
    float inv = 1.0f/(e0+e1+e2);
    float gamma = 1.0f + softplusf_(c[3*H*W + 5*H + h]);
    float* sc = scal + bid*8;
    sc[0]=beta; sc[1]=gate; sc[2]=e0*inv; sc[3]=e1*inv; sc[4]=e2*inv; sc[5]=gamma; sc[6]=knorm;
  }
}

// ---- kernel 2: beta-scaled cosine scores [B,H,N] ----
// 16 lanes per memory row (8 floats each via 2x float4); one wave = 4 rows at a
// time; butterfly is 4 steps over 16 lanes shared across the wave's rows.
// Plain (cached) loads: memory's tail should stay L3-resident for final_kernel's
// reversed walk.
__global__ __launch_bounds__(256) void scores_kernel(const float* __restrict__ memory,
    const float* __restrict__ keys_t, const float* __restrict__ scal,
    float* __restrict__ scores){
  int b = blockIdx.y;
  int n0 = blockIdx.x * 64;
  int tid = threadIdx.x;
  int grp = tid >> 4, l16 = tid & 15;     // 16 groups of 16 lanes
  __shared__ __align__(16) float kk[H][W];
  __shared__ float kbeta[H], kn[H];
  for (int i = tid; i < H*W; i += 256) kk[0][i] = keys_t[(size_t)b*H*W + i];
  if (tid < H){ kbeta[tid] = scal[(b*H+tid)*8 + 0]; kn[tid] = scal[(b*H+tid)*8 + 6]; }
  __syncthreads();
  float4 ka[H], kb[H];
  #pragma unroll
  for (int h=0;h<H;h++){
    ka[h] = *(const float4*)&kk[h][l16*8];
    kb[h] = *(const float4*)&kk[h][l16*8+4];
  }
  float beta_l = (l16 < H) ? kbeta[l16] : 0.0f;
  float kn_l   = (l16 < H) ? kn[l16]    : 1.0f;
  #pragma unroll
  for (int it=0; it<4; ++it){
    int n = n0 + it*16 + grp;
    const float4* mp = (const float4*)(memory + ((size_t)b*N + n)*W + l16*8);
    float4 ma = mp[0], mb = mp[1];
    float msq = ma.x*ma.x+ma.y*ma.y+ma.z*ma.z+ma.w*ma.w
              + mb.x*mb.x+mb.y*mb.y+mb.z*mb.z+mb.w*mb.w;
    float d0 = ma.x*ka[0].x+ma.y*ka[0].y+ma.z*ka[0].z+ma.w*ka[0].w
             + mb.x*kb[0].x+mb.y*kb[0].y+mb.z*kb[0].z+mb.w*kb[0].w;
    float d1 = ma.x*ka[1].x+ma.y*ka[1].y+ma.z*ka[1].z+ma.w*ka[1].w
             + mb.x*kb[1].x+mb.y*kb[1].y+mb.z*kb[1].z+mb.w*kb[1].w;
    float d2 = ma.x*ka[2].x+ma.y*ka[2].y+ma.z*ka[2].z+ma.w*ka[2].w
             + mb.x*kb[2].x+mb.y*kb[2].y+mb.z*kb[2].z+mb.w*kb[2].w;
    float d3 = ma.x*ka[3].x+ma.y*ka[3].y+ma.z*ka[3].z+ma.w*ka[3].w
             + mb.x*kb[3].x+mb.y*kb[3].y+mb.z*kb[3].z+mb.w*kb[3].w;
    #pragma unroll
    for (int off=1; off<16; off<<=1){
      msq += __shfl_xor(msq, off);
      d0  += __shfl_xor(d0 , off);
      d1  += __shfl_xor(d1 , off);
      d2  += __shfl_xor(d2 , off);
      d3  += __shfl_xor(d3 , off);
    }
    if (l16 < H){
      float dd = (l16==0)?d0 : (l16==1)?d1 : (l16==2)?d2 : d3;
      float mn = sqrtf(msq);
      scores[((size_t)(b*H + l16))*N + n] = beta_l*dd/(kn_l*mn + EPSF);
    }
  }
}

// ---- kernel 3: softmax -> interp -> circular conv -> sharpen -> write_dist ----
// grid = B*H blocks, 256 threads, float4 everywhere. wd may alias scores:
// every thread's global reads precede its global writes (barriers between).
__global__ __launch_bounds__(256) void dist_kernel(const float* scores,
    const float* __restrict__ pw, const float* __restrict__ scal, float* wd){
  int bh = blockIdx.x;
  int h = bh & (H-1);
  int tid = threadIdx.x;
  __shared__ __align__(16) float buf[N];    // 16 KB
  __shared__ float red[4];
  const float4* srow4 = (const float4*)(scores + (size_t)bh*N);

  float4 v[4]; float lmax = -1e30f;
  #pragma unroll
  for (int j=0;j<4;j++){
    v[j] = srow4[tid + 256*j];
    lmax = fmaxf(lmax, fmaxf(fmaxf(v[j].x,v[j].y), fmaxf(v[j].z,v[j].w)));
  }
  float smax = blockReduceMax256(lmax, red);
  float lsum = 0.0f;
  #pragma unroll
  for (int j=0;j<4;j++){
    v[j].x = expf(v[j].x-smax); v[j].y = expf(v[j].y-smax);
    v[j].z = expf(v[j].z-smax); v[j].w = expf(v[j].w-smax);
    lsum += v[j].x+v[j].y+v[j].z+v[j].w;
  }
  float ssum = blockReduceSum256(lsum, red);

  float gate = scal[bh*8+1];
  float ga = gate/ssum, gb = 1.0f - gate;
  const float4* prow4 = (const float4*)(pw + (size_t)h*N);
  #pragma unroll
  for (int j=0;j<4;j++){
    float4 p = prow4[tid + 256*j];
    float4 o;
    o.x = ga*v[j].x + gb*p.x;  o.y = ga*v[j].y + gb*p.y;
    o.z = ga*v[j].z + gb*p.z;  o.w = ga*v[j].w + gb*p.w;
    ((float4*)buf)[tid + 256*j] = o;
  }
  __syncthreads();

  float s0 = scal[bh*8+2], s1 = scal[bh*8+3], s2 = scal[bh*8+4], gamma = scal[bh*8+5];
  float4 q[4]; float qsum = 0.0f;
  #pragma unroll
  for (int j=0;j<4;j++){
    int m = 4*(tid + 256*j);
    float4 c = *(const float4*)&buf[m];
    float wm = buf[(m + N - 1) & (N-1)];
    float wp = buf[(m + 4) & (N-1)];
    float t0 = s0*wm  + s1*c.x + s2*c.y;
    float t1 = s0*c.x + s1*c.y + s2*c.z;
    float t2 = s0*c.y + s1*c.z + s2*c.w;
    float t3 = s0*c.z + s1*c.w + s2*wp;
    // wsft strictly > 0 (convex mix of positive softmaxes, shift wts >= 0 sum 1)
    q[j].x = pospowf_(t0, gamma); q[j].y = pospowf_(t1, gamma);
    q[j].z = pospowf_(t2, gamma); q[j].w = pospowf_(t3, gamma);
    qsum += q[j].x+q[j].y+q[j].z+q[j].w;
  }
  float tot = blockReduceSum256(qsum, red);
  float inv = 1.0f/(tot + EPSF);
  float4* wrow4 = (float4*)(wd + (size_t)bh*N);
  #pragma unroll
  for (int j=0;j<4;j++)
    wrow4[tid + 256*j] = make_float4(q[j].x*inv, q[j].y*inv, q[j].z*inv, q[j].w*inv);
}

// ---- kernel 4: out = memory * prod_h(1 - wd*erase) + sum_h wd*write ----
// Reversed traversal (memory tail still L3-resident after scores' forward
// stream) + NONTEMPORAL out stores (never re-read; keeps out from evicting
// memory lines from L3) + NONTEMPORAL memory loads (last use; NT loads still
// hit L3 but don't retain). Row loop fully unrolled so all 8 global loads
// issue before the compute chain.
__global__ __launch_bounds__(256) void final_kernel(const float* __restrict__ memory,
    const float* __restrict__ wd, const float* __restrict__ erase_s,
    const float* __restrict__ write_t, float* __restrict__ out){
  int b  = (B-1) - blockIdx.y;
  int n0 = ((N/64-1) - blockIdx.x) * 64;
  int tid = threadIdx.x;
  __shared__ __align__(16) float esh[H][W];
  __shared__ __align__(16) float wsh[H][W];
  __shared__ float wdsh[H][64];
  for (int i=tid;i<H*W;i+=256){ esh[0][i] = erase_s[(size_t)b*H*W+i]; wsh[0][i] = write_t[(size_t)b*H*W+i]; }
  for (int i=tid;i<H*64;i+=256){ int h=i>>6, r=i&63; wdsh[h][r] = wd[((size_t)(b*H+h))*N + n0 + r]; }
  __syncthreads();
  int wq = (tid & 31) * 4;   // float4 column
  int rl = tid >> 5;         // row-in-group 0..7
  #pragma unroll
  for (int rr = 0; rr < 8; ++rr){
    int r = rl + rr*8;
    int n = n0 + r;
    size_t base = ((size_t)b*N + n)*W + wq;
    f32x4 m = __builtin_nontemporal_load((const f32x4*)(memory + base));
    float px=1.f, py=1.f, pz=1.f, pwv=1.f;
    float ux=0.f, uy=0.f, uz=0.f, uw=0.f;
    #pragma unroll
    for (int h=0;h<H;h++){
      float d = wdsh[h][r];
      float4 e  = *(const float4*)&esh[h][wq];
      float4 wv = *(const float4*)&wsh[h][wq];
      px *= 1.0f - d*e.x;  py *= 1.0f - d*e.y;
      pz *= 1.0f - d*e.z;  pwv*= 1.0f - d*e.w;
      ux += d*wv.x;  uy += d*wv.y;  uz += d*wv.z;  uw += d*wv.w;
    }
    f32x4 o;
    o.x = m.x*px + ux;  o.y = m.y*py + uy;
    o.z = m.z*pz + uz;  o.w = m.w*pwv + uw;
    __builtin_nontemporal_store(o, (f32x4*)(out + base));
  }
}

extern "C" void kernel_launch(void* const* d_in, const int* in_sizes, int n_in,
                              void* d_out, int out_size, void* d_ws, size_t ws_size,
                              hipStream_t stream){
  const float* memory   = (const float*)d_in[0];
  const float* controls = (const float*)d_in[1];
  const float* bias     = (const float*)d_in[2];
  float* out = (float*)d_out;

  float* ws      = (float*)d_ws;
  float* keys_t  = ws;                    // B*H*W
  float* erase_s = keys_t  + B*H*W;       // B*H*W
  float* write_t = erase_s + B*H*W;       // B*H*W
  float* scal    = write_t + B*H*W;       // B*H*8
  float* pw      = scal    + B*H*8;       // H*N (prev_weights = softmax(bias))
  float* scores  = pw      + H*N;         // B*H*N
  float* wd      = scores;                // aliased over scores (safe, see dist_kernel)
  // total ws use: 3*65536 + 4096 + 16384 + 2097152 floats ≈ 8.9 MB

  prep_kernel  <<<dim3(B*H + H),  dim3(128), 0, stream>>>(controls, keys_t, erase_s, write_t, scal, bias, pw);
  scores_kernel<<<dim3(N/64, B),  dim3(256), 0, stream>>>(memory, keys_t, scal, scores);
  dist_kernel  <<<dim3(B*H),      dim3(256), 0, stream>>>(scores, pw, scal, wd);
  final_kernel <<<dim3(N/64, B),  dim3(256), 0, stream>>>(memory, wd, erase_s, write_t, out);
}